// Round 1
// baseline (375.131 us; speedup 1.0000x reference)
//
#include <hip/hip_runtime.h>
#include <math.h>

// x [N=2048, C=512, H*W=49] fp32.
// Two-pass: (A) compute gate[n,c] (4 MB, workspace), (B) out = x * gate.
// x (205 MB) fits the 256 MB Infinity Cache, so pass B's re-read of x is
// L3-absorbed; HBM traffic stays ~= read-once + write-once.

#define NN 2048
#define CC 512
#define HW 49
#define CHCH 128            // channels per chunk
#define CHEL (CHCH * HW)    // 6272 floats per chunk (24.5 KB LDS)
#define CHV4 (CHEL / 4)     // 1568 float4 per chunk
#define NCHUNK (CC / CHCH)  // 4
#define EPS 1e-5f

// ---- Pass A: per-sample channel means -> mean/var -> gate[n,c] ----
__global__ __launch_bounds__(512) void stats_kernel(const float* __restrict__ x,
                                                    float* __restrict__ gate) {
    __shared__ float lds[CHEL];
    __shared__ float wsum[8];
    __shared__ float wsum2[8];
    __shared__ float s_m, s_inv;

    const int n = blockIdx.x;
    const int tid = threadIdx.x;                 // == channel owned by this thread
    const size_t nbase = (size_t)n * (CC * HW);
    const float4* __restrict__ xin4 = (const float4*)(x + nbase);

    float y = 0.0f;
    for (int j = 0; j < NCHUNK; ++j) {
        for (int i = tid; i < CHV4; i += 512) {
            ((float4*)lds)[i] = xin4[j * CHV4 + i];
        }
        __syncthreads();
        if ((tid >> 7) == j) {                   // 2 waves own this chunk
            const int base = (tid & (CHCH - 1)) * HW;  // stride 49: conflict-free
            float s = 0.0f;
#pragma unroll
            for (int l = 0; l < HW; ++l) s += lds[base + l];
            y = s * (1.0f / (float)HW);
        }
        __syncthreads();
    }

    float sum = y, sum2 = y * y;
#pragma unroll
    for (int off = 32; off > 0; off >>= 1) {
        sum  += __shfl_down(sum, off);
        sum2 += __shfl_down(sum2, off);
    }
    const int wave = tid >> 6;
    const int lane = tid & 63;
    if (lane == 0) { wsum[wave] = sum; wsum2[wave] = sum2; }
    __syncthreads();
    if (tid == 0) {
        float ts = 0.0f, ts2 = 0.0f;
#pragma unroll
        for (int w = 0; w < 8; ++w) { ts += wsum[w]; ts2 += wsum2[w]; }
        const float m = ts * (1.0f / (float)CC);
        float var = ts2 * (1.0f / (float)CC) - m * m;
        var = fmaxf(var, 0.0f);
        s_m = m;
        s_inv = rsqrtf(var + EPS);
    }
    __syncthreads();

    const float yn = (y - s_m) * s_inv;
    gate[(size_t)n * CC + tid] = expf(-yn * yn);  // C_PARAM=2 -> exp(-0.5*2*yn^2)
}

// ---- Pass B: out[e] = x[e] * gate[e / 49], one float4 per thread ----
__global__ __launch_bounds__(256) void apply_kernel(const float* __restrict__ x,
                                                    const float* __restrict__ gate,
                                                    float* __restrict__ out) {
    const unsigned i  = blockIdx.x * 256u + threadIdx.x;  // float4 index
    const unsigned e0 = i * 4u;
    const unsigned d0 = e0 / 49u;                          // magic-mul division
    const unsigned r0 = e0 - d0 * 49u;                     // 0..48

    const float4 v = ((const float4*)x)[i];
    const float g0 = gate[d0];
    // A float4 straddles at most one channel boundary (49 > 4).
    // Last float4 of the array has r0 == 45, so d0+1 is never read OOB.
    const float g1 = (r0 >= 46u) ? gate[d0 + 1] : g0;

    float4 o;
    o.x = v.x * g0;                          // r0+0 >= 49 impossible
    o.y = v.y * ((r0 >= 48u) ? g1 : g0);
    o.z = v.z * ((r0 >= 47u) ? g1 : g0);
    o.w = v.w * ((r0 >= 46u) ? g1 : g0);
    ((float4*)out)[i] = o;
}

extern "C" void kernel_launch(void* const* d_in, const int* in_sizes, int n_in,
                              void* d_out, int out_size, void* d_ws, size_t ws_size,
                              hipStream_t stream) {
    const float* x = (const float*)d_in[0];
    float* out = (float*)d_out;
    float* gate = (float*)d_ws;                 // 2048*512*4 = 4 MB in workspace

    stats_kernel<<<NN, 512, 0, stream>>>(x, gate);

    const int total4 = NN * CC * HW / 4;        // 12,845,056 float4
    apply_kernel<<<total4 / 256, 256, 0, stream>>>(x, gate, out);  // 50176 blocks
}

// Round 2
// 359.460 us; speedup vs baseline: 1.0436x; 1.0436x over previous
//
#include <hip/hip_runtime.h>
#include <math.h>

// x [N=2048, C=512, H*W=49] fp32.
// Fused single-pass: per-sample channel means via chunked LDS transpose,
// block stats -> gate[c] in LDS, then apply by RE-READING x from global.
// The re-read hits L2/L3 (the block fetched its own 98 KB ~8 us earlier;
// only ~50 MB of device-wide traffic intervenes, << 256 MB L3), so HBM
// traffic stays ~= read-once (205 MB) + write-once (205 MB).
//
// vs round 0 (345 us): drops the v[49] register hoard and the store-side
// LDS transpose round trip -> 18 barriers -> 11, ~2 blocks/CU -> 4.
// vs round 1 (375 us): re-read is per-block-hot, not device-cold; 1 dispatch.

#define NN 2048
#define CC 512
#define HW 49
#define CHCH 128            // channels per chunk
#define CHEL (CHCH * HW)    // 6272 floats per chunk (25 KB LDS)
#define CHV4 (CHEL / 4)     // 1568 float4 per chunk
#define NCHUNK (CC / CHCH)  // 4
#define SV4 (CC * HW / 4)   // 6272 float4 per sample
#define EPS 1e-5f

__global__ __launch_bounds__(512) void gate_kernel(const float* __restrict__ x,
                                                   float* __restrict__ out) {
    __shared__ float lds[CHEL];
    __shared__ float gate_s[CC];
    __shared__ float wsum[8], wsum2[8];
    __shared__ float s_m, s_inv;

    const int n = blockIdx.x;
    const int tid = threadIdx.x;               // == channel owned by this thread
    const size_t nbase = (size_t)n * (CC * HW);
    const float4* __restrict__ xin4 = (const float4*)(x + nbase);

    // ---- Phase 1: chunked coalesced stage -> per-channel spatial mean ----
    float y = 0.0f;
    for (int j = 0; j < NCHUNK; ++j) {
        for (int i = tid; i < CHV4; i += 512)
            ((float4*)lds)[i] = xin4[j * CHV4 + i];
        __syncthreads();
        if ((tid >> 7) == j) {                 // 2 waves own this chunk's channels
            const int base = (tid & (CHCH - 1)) * HW;  // stride 49 -> 2-way max, free
            float s = 0.0f;
#pragma unroll
            for (int l = 0; l < HW; ++l) s += lds[base + l];
            y = s * (1.0f / (float)HW);
        }
        __syncthreads();
    }

    // ---- Phase 2: block mean/var -> per-channel gate in LDS ----
    float sum = y, sum2 = y * y;
#pragma unroll
    for (int off = 32; off > 0; off >>= 1) {
        sum  += __shfl_down(sum, off);
        sum2 += __shfl_down(sum2, off);
    }
    if ((tid & 63) == 0) { wsum[tid >> 6] = sum; wsum2[tid >> 6] = sum2; }
    __syncthreads();
    if (tid == 0) {
        float ts = 0.0f, ts2 = 0.0f;
#pragma unroll
        for (int w = 0; w < 8; ++w) { ts += wsum[w]; ts2 += wsum2[w]; }
        const float m = ts * (1.0f / (float)CC);
        float var = fmaxf(ts2 * (1.0f / (float)CC) - m * m, 0.0f);
        s_m = m;
        s_inv = rsqrtf(var + EPS);
    }
    __syncthreads();
    const float yn = (y - s_m) * s_inv;
    gate_s[tid] = expf(-yn * yn);              // C_PARAM=2 -> exp(-0.5*2*yn^2)
    __syncthreads();

    // ---- Phase 3: apply gate, re-reading x (L2/L3-hot), fully coalesced ----
    float4* __restrict__ out4 = (float4*)(out + nbase);
    for (int i = tid; i < SV4; i += 512) {
        const float4 v = xin4[i];
        const unsigned e0 = 4u * (unsigned)i;
        const unsigned d0 = e0 / 49u;          // magic-mul division
        const unsigned r0 = e0 - d0 * 49u;     // 0..48
        const float g0 = gate_s[d0];
        // float4 straddles at most one channel boundary (49 > 4);
        // last float4 has r0 == 45 -> gate_s[d0+1] never OOB (d0 <= 510 when read).
        const float g1 = (r0 >= 46u) ? gate_s[d0 + 1] : g0;
        float4 o;
        o.x = v.x * g0;
        o.y = v.y * ((r0 >= 48u) ? g1 : g0);
        o.z = v.z * ((r0 >= 47u) ? g1 : g0);
        o.w = v.w * ((r0 >= 46u) ? g1 : g0);
        out4[i] = o;
    }
}

extern "C" void kernel_launch(void* const* d_in, const int* in_sizes, int n_in,
                              void* d_out, int out_size, void* d_ws, size_t ws_size,
                              hipStream_t stream) {
    const float* x = (const float*)d_in[0];
    float* out = (float*)d_out;
    gate_kernel<<<NN, 512, 0, stream>>>(x, out);
}